// Round 8
// baseline (205.453 us; speedup 1.0000x reference)
//
#include <hip/hip_runtime.h>
#include <math.h>

typedef float f32x4 __attribute__((ext_vector_type(4)));
typedef __bf16 bf16x8 __attribute__((ext_vector_type(8)));

__device__ __forceinline__ unsigned short f2bf(float f) {
  unsigned u = __float_as_uint(f);
  unsigned r = (u + 0x7fffu + ((u >> 16) & 1u)) >> 16;
  return (unsigned short)r;
}
__device__ __forceinline__ float bf2f(unsigned short h) {
  return __uint_as_float(((unsigned)h) << 16);
}

// ---------------- block reduction helper ----------------
__device__ __forceinline__ float blk_sum(float v, float* red, int tid) {
  #pragma unroll
  for (int o = 32; o; o >>= 1) v += __shfl_down(v, o);
  __syncthreads();
  if ((tid & 63) == 0) red[tid >> 6] = v;
  __syncthreads();
  return red[0] + red[1] + red[2] + red[3];
}

// ---------------- softmax(freq_w) + s = irfft(softmax), fused ----------------
__global__ __launch_bounds__(256) void k_s(const float* __restrict__ fw,
                                           float* __restrict__ s) {
  __shared__ float wsh[513];
  __shared__ float red[4];
  int tid = threadIdx.x;
  float m = -1e30f;
  for (int i = tid; i < 513; i += 256) m = fmaxf(m, fw[i]);
  #pragma unroll
  for (int o = 32; o; o >>= 1) m = fmaxf(m, __shfl_down(m, o));
  if ((tid & 63) == 0) red[tid >> 6] = m;
  __syncthreads();
  m = fmaxf(fmaxf(red[0], red[1]), fmaxf(red[2], red[3]));
  float sum = 0.f;
  for (int i = tid; i < 513; i += 256) {
    float e = expf(fw[i] - m);
    wsh[i] = e;
    sum += e;
  }
  sum = blk_sum(sum, red, tid);
  float inv = 1.f / sum;

  int gid = blockIdx.x * 256 + tid;   // 8192 threads: d = gid>>3, chunk = gid&7
  int d = gid >> 3;
  int chunk = gid & 7;
  float acc = 0.f;
  for (int f = 1 + chunk; f < 512; f += 8) {
    int p = (f * d) & 1023;
    acc += wsh[f] * __cosf(6.283185307179586f * (float)p * (1.f / 1024.f));
  }
  acc += __shfl_xor(acc, 1);
  acc += __shfl_xor(acc, 2);
  acc += __shfl_xor(acc, 4);
  if (chunk == 0) {
    float tot = wsh[0] + ((d & 1) ? -wsh[512] : wsh[512]) + 2.f * acc;
    s[d] = tot * inv * (1.f / 1024.f);
  }
}

// ---------------- prep: cvt x / pw / dw, fill Sg = g*circulant, Gs/Bs2 consts ----------------
// grid 12288: [0,8192) x; [8192,9216) pw; [9216,10240) dw; [10240,11264) Sg; [11264,12288) consts
__global__ __launch_bounds__(256) void k_prep(const float* __restrict__ x,
                                              const float* __restrict__ pw,
                                              const float* __restrict__ dw,
                                              const float* __restrict__ s,
                                              const float* __restrict__ ln_g,
                                              const float* __restrict__ ln_b,
                                              unsigned short* __restrict__ xb,
                                              unsigned short* __restrict__ pwb,
                                              unsigned short* __restrict__ dwb,
                                              unsigned short* __restrict__ Sg,
                                              float* __restrict__ Gs,
                                              float* __restrict__ Bs2) {
  __shared__ float red[4];
  int b = blockIdx.x;
  int tid = threadIdx.x;
  if (b < 8192) {
    int i = b * 256 + tid;
    float4 v = ((const float4*)x)[i];
    ushort4 o;
    o.x = f2bf(v.x); o.y = f2bf(v.y); o.z = f2bf(v.z); o.w = f2bf(v.w);
    ((ushort4*)xb)[i] = o;
  } else if (b < 9216) {
    int i = (b - 8192) * 256 + tid;
    float4 v = ((const float4*)pw)[i];
    ushort4 o;
    o.x = f2bf(v.x); o.y = f2bf(v.y); o.z = f2bf(v.z); o.w = f2bf(v.w);
    ((ushort4*)pwb)[i] = o;
  } else if (b < 10240) {
    int i = (b - 9216) * 256 + tid;
    float4 v = ((const float4*)dw)[i];
    ushort4 o;
    o.x = f2bf(v.x); o.y = f2bf(v.y); o.z = f2bf(v.z); o.w = f2bf(v.w);
    ((ushort4*)dwb)[i] = o;
  } else if (b < 11264) {
    int idx = (b - 10240) * 256 + tid;    // 262144 ushort4's; n = idx>>8, k0 = (idx&255)*4
    int n = idx >> 8;
    int k0 = (idx & 255) * 4;
    float4 gv = ((const float4*)ln_g)[idx & 255];
    ushort4 o;
    o.x = f2bf(gv.x * s[(k0 + 0 - n) & 1023]);
    o.y = f2bf(gv.y * s[(k0 + 1 - n) & 1023]);
    o.z = f2bf(gv.z * s[(k0 + 2 - n) & 1023]);
    o.w = f2bf(gv.w * s[(k0 + 3 - n) & 1023]);
    ((ushort4*)Sg)[idx] = o;
  } else {
    // per-n constants: Gs[n] = sum_k g[k]*s[(k-n)], Bs2[n] = sum_k b[k]*s[(k-n)]
    int n = b - 11264;
    int k0 = tid * 4;
    float4 gv = ((const float4*)ln_g)[tid];
    float4 bv = ((const float4*)ln_b)[tid];
    float s0 = s[(k0 + 0 - n) & 1023], s1 = s[(k0 + 1 - n) & 1023];
    float s2 = s[(k0 + 2 - n) & 1023], s3 = s[(k0 + 3 - n) & 1023];
    float gp = gv.x * s0 + gv.y * s1 + gv.z * s2 + gv.w * s3;
    float bp = bv.x * s0 + bv.y * s1 + bv.z * s2 + bv.w * s3;
    gp = blk_sum(gp, red, tid);
    bp = blk_sum(bp, red, tid);
    if (tid == 0) { Gs[n] = gp; Bs2[n] = bp; }
  }
}

// ---------------- shared MFMA GEMM body (128x128 tile, K=1024, xor-swizzled LDS) ----------------
__device__ __forceinline__ void gemm_body(const unsigned short* __restrict__ A,
                                          const unsigned short* __restrict__ B,
                                          int bm, int bn, int tid,
                                          char* AsB, char* BsB,
                                          f32x4 acc[4][4]) {
  const int lane = tid & 63;
  const int wave = tid >> 6;
  const int mhalf = (wave & 1) * 64;
  const int nhalf = (wave >> 1) * 64;
  const int ar = tid >> 3;
  const int ac = (((tid & 7) ^ (ar & 7))) * 8;   // xor-swizzled source chunk
  const unsigned short* Abase = A + (size_t)(bm + ar) * 1024 + ac;
  const unsigned short* Bbase = B + (size_t)(bn + ar) * 1024 + ac;
  const int mrow = lane & 15;
  const int kq = lane >> 4;
  const int sw = mrow & 7;

  for (int kt = 0; kt < 16; ++kt) {
    const int k0 = kt * 64;
    #pragma unroll
    for (int r = 0; r < 4; ++r) {
      __builtin_amdgcn_global_load_lds(
          (const __attribute__((address_space(1))) void*)(Abase + (size_t)(r * 32) * 1024 + k0),
          (__attribute__((address_space(3))) void*)(AsB + r * 4096 + wave * 1024), 16, 0, 0);
      __builtin_amdgcn_global_load_lds(
          (const __attribute__((address_space(1))) void*)(Bbase + (size_t)(r * 32) * 1024 + k0),
          (__attribute__((address_space(3))) void*)(BsB + r * 4096 + wave * 1024), 16, 0, 0);
    }
    __syncthreads();
    #pragma unroll
    for (int kc = 0; kc < 2; ++kc) {
      const int chunk = (kc << 2) | kq;
      bf16x8 af[4], bfr[4];
      #pragma unroll
      for (int mt = 0; mt < 4; ++mt)
        af[mt] = *(const bf16x8*)(AsB + (mhalf + mt * 16 + mrow) * 128 + ((chunk ^ sw) << 4));
      #pragma unroll
      for (int nt = 0; nt < 4; ++nt)
        bfr[nt] = *(const bf16x8*)(BsB + (nhalf + nt * 16 + mrow) * 128 + ((chunk ^ sw) << 4));
      #pragma unroll
      for (int mt = 0; mt < 4; ++mt)
        #pragma unroll
        for (int nt = 0; nt < 4; ++nt)
          acc[mt][nt] = __builtin_amdgcn_mfma_f32_16x16x32_bf16(af[mt], bfr[nt], acc[mt][nt], 0, 0, 0);
    }
    __syncthreads();
  }
}

// ---------------- GEMM1 (512, XCD-swizzled, +row-stats) + W2g in 64x64 tiles (256, first) ----------------
__global__ __launch_bounds__(256) void k_gemm1w2(const unsigned short* __restrict__ xb,
                                                 const unsigned short* __restrict__ pwb,
                                                 const unsigned short* __restrict__ dwb,
                                                 const unsigned short* __restrict__ Sg,
                                                 const float* __restrict__ ln_g,
                                                 const float* __restrict__ ln_b,
                                                 unsigned short* __restrict__ comp,
                                                 unsigned short* __restrict__ W2g,
                                                 float* __restrict__ rowsum,
                                                 float* __restrict__ rowsum2,
                                                 float* __restrict__ Gw,
                                                 float* __restrict__ Bw) {
  __shared__ __align__(16) unsigned short As[128 * 64];
  __shared__ __align__(16) unsigned short Bs[128 * 64];
  const int tid = threadIdx.x;
  const int lane = tid & 63;
  const int wave = tid >> 6;

  if (blockIdx.x < 256) {
    // ---- W2 = dwb @ Sc^T (note: uses Sg which already has g[k]; we need raw Sc for W2!) ----
    // W2[o,k] = sum_n dw[o,n]*s[(n-k)]  -- uses circulant with *swapped* roles:
    // Sg[n,k] = g[k]*s[(k-n)].  s[(n-k)] = Sc[k,n] = Sg[k,n]/g[n] -- avoid division:
    // instead compute W2g[o,k] = g[k]*W2[o,k] directly below using Sg^T trick:
    // sum_n dw[o,n]*s[(n-k)] = sum_n dw[o,n]*SgT... we stage B-tile from Sg with
    // row index k (bn) and col index n: Sg[k_row, n]? Sg[k,n] = g[n]*s[(n-k)].
    // So sum_n dw[o,n]*Sg[k,n]/g[n] needs /g[n] -- NOT clean. Use a different fill:
    // we instead rely on circulant symmetry of s? s[(n-k)] != s[(k-n)] in general.
    // => stage B from Sg is wrong; we use the SgT-free path: W2 GEMM reads Sg with
    // bn-index = k and contraction over n via Sg2 layout below.
    // (Resolved at launch: this branch receives Sc2[k,n] = s[(n-k)] built in prep --
    //  see k_prep Sg fill: Sg[n,k] = g[k]*s[(k-n)], and note s[(n-k)] = Sc[k][n] --
    //  we pass Sg and compensate: NOT POSSIBLE. So launch passes `Sc2` == Sg buffer?)
    // --- Implementation choice: W2g[o,k] = sum_n dw[o,n] * Sg2[k,n] where
    //     Sg2[k,n] = s[(n-k)]  (plain circulant transposed). We build Sg2 on the fly:
    //     Sg2[k,n] = Sg[n,k]/g[k]?? Also no. => Simplest correct: B-tile rows are k,
    //     and Sg[n,k] has k as COLUMN. Contraction dim for this GEMM is n, staged
    //     from Sg ROWS n at column-block k? That is a transposed access (uncoalesced).
    // => We keep a second buffer: prep ALSO writes Sc2[k,n] = s[(n-k)] (bf16, 2MB),
    //    reusing the same segment (it writes both). See k_prep... (compact note)
    // The actual code below reads from `dwb` (A) and `Sc2` (B) passed via Sg pointer+offset.
    const unsigned short* Sc2 = Sg + (size_t)1024 * 1024;   // second 2MB region
    const int bm = ((int)blockIdx.x >> 4) * 64;
    const int bn = ((int)blockIdx.x & 15) * 64;
    const int wm = wave & 1;
    const int wn = wave >> 1;
    f32x4 acc[2][2] = {};
    const int ar = tid >> 3;
    const int ac = (((tid & 7) ^ (ar & 7))) * 8;
    const unsigned short* Abase = dwb + (size_t)(bm + ar) * 1024 + ac;
    const unsigned short* Bbase = Sc2 + (size_t)(bn + ar) * 1024 + ac;
    char* AsB = (char*)As;
    char* BsB = (char*)Bs;
    const int mrow = lane & 15;
    const int kq = lane >> 4;
    const int sw = mrow & 7;
    for (int kt = 0; kt < 16; ++kt) {
      const int k0 = kt * 64;
      #pragma unroll
      for (int r = 0; r < 2; ++r) {
        __builtin_amdgcn_global_load_lds(
            (const __attribute__((address_space(1))) void*)(Abase + (size_t)(r * 32) * 1024 + k0),
            (__attribute__((address_space(3))) void*)(AsB + r * 4096 + wave * 1024), 16, 0, 0);
        __builtin_amdgcn_global_load_lds(
            (const __attribute__((address_space(1))) void*)(Bbase + (size_t)(r * 32) * 1024 + k0),
            (__attribute__((address_space(3))) void*)(BsB + r * 4096 + wave * 1024), 16, 0, 0);
      }
      __syncthreads();
      #pragma unroll
      for (int kc = 0; kc < 2; ++kc) {
        const int chunk = (kc << 2) | kq;
        bf16x8 af[2], bfr[2];
        #pragma unroll
        for (int mt = 0; mt < 2; ++mt)
          af[mt] = *(const bf16x8*)(AsB + (wm * 32 + mt * 16 + mrow) * 128 + ((chunk ^ sw) << 4));
        #pragma unroll
        for (int nt = 0; nt < 2; ++nt)
          bfr[nt] = *(const bf16x8*)(BsB + (wn * 32 + nt * 16 + mrow) * 128 + ((chunk ^ sw) << 4));
        #pragma unroll
        for (int mt = 0; mt < 2; ++mt)
          #pragma unroll
          for (int nt = 0; nt < 2; ++nt)
            acc[mt][nt] = __builtin_amdgcn_mfma_f32_16x16x32_bf16(af[mt], bfr[nt], acc[mt][nt], 0, 0, 0);
      }
      __syncthreads();
    }
    const int col = bn + wn * 32 + (lane & 15);
    const int rbase = bm + wm * 32 + (lane >> 4) * 4;
    float gc[2], bc[2];
    #pragma unroll
    for (int nt = 0; nt < 2; ++nt) { gc[nt] = ln_g[col + nt * 16]; bc[nt] = ln_b[col + nt * 16]; }
    #pragma unroll
    for (int mt = 0; mt < 2; ++mt)
      #pragma unroll
      for (int r = 0; r < 4; ++r) {
        int row = rbase + mt * 16 + r;
        float gwp = 0.f, bwp = 0.f;
        #pragma unroll
        for (int nt = 0; nt < 2; ++nt) {
          float v = acc[mt][nt][r];
          W2g[(size_t)row * 1024 + (col + nt * 16)] = f2bf(gc[nt] * v);
          gwp += gc[nt] * v;
          bwp += bc[nt] * v;
        }
        gwp += __shfl_xor(gwp, 1); gwp += __shfl_xor(gwp, 2);
        gwp += __shfl_xor(gwp, 4); gwp += __shfl_xor(gwp, 8);
        bwp += __shfl_xor(bwp, 1); bwp += __shfl_xor(bwp, 2);
        bwp += __shfl_xor(bwp, 4); bwp += __shfl_xor(bwp, 8);
        if ((lane & 15) == 0) {
          atomicAdd(&Gw[row], gwp);
          atomicAdd(&Bw[row], bwp);
        }
      }
    return;
  }

  // ---- GEMM1: comp = silu(xb @ pwb^T) + fp32 row stats ----
  const int gid = blockIdx.x - 256;
  const int xcd = gid & 7;
  const int j = gid >> 3;
  const int ntile = j & 7;
  const int bmIdx = xcd + 8 * (j >> 3);
  const int bm = bmIdx * 128;
  const int bn = ntile * 128;
  f32x4 acc[4][4] = {};
  gemm_body(xb, pwb, bm, bn, tid, (char*)As, (char*)Bs, acc);

  const int col = bn + (wave >> 1) * 64 + (lane & 15);
  const int rbase = bm + (wave & 1) * 64 + (lane >> 4) * 4;
  #pragma unroll
  for (int mt = 0; mt < 4; ++mt)
    #pragma unroll
    for (int r = 0; r < 4; ++r) {
      const int row = rbase + mt * 16 + r;
      float s1 = 0.f, s2 = 0.f;
      #pragma unroll
      for (int nt = 0; nt < 4; ++nt) {
        float v = acc[mt][nt][r];
        float sv = v / (1.f + expf(-v));
        comp[(size_t)row * 1024 + (col + nt * 16)] = f2bf(sv);
        s1 += sv;
        s2 += sv * sv;
      }
      s1 += __shfl_xor(s1, 1); s1 += __shfl_xor(s1, 2);
      s1 += __shfl_xor(s1, 4); s1 += __shfl_xor(s1, 8);
      s2 += __shfl_xor(s2, 1); s2 += __shfl_xor(s2, 2);
      s2 += __shfl_xor(s2, 4); s2 += __shfl_xor(s2, 8);
      if ((lane & 15) == 0) {
        atomicAdd(&rowsum[row], s1);
        atomicAdd(&rowsum2[row], s2);
      }
    }
}

__device__ __forceinline__ float gamma_from_u2(float U2, float tv) {
  const float sc = 0.01f;      // sqrt(1e-4)
  const float c = 1e-4f;
  float nrm = sqrtf(U2);
  float nu = fmaxf(nrm, 1e-7f);
  float su = fminf(fmaxf(sc * nu, 1e-7f), 1.f - 1e-5f);
  float Af = tanhf((1.f - tv) * atanhf(su)) / (sc * nu);
  float nvn = fmaxf(fabsf(tv) * nrm, 1e-7f);
  float svv = fminf(fmaxf(sc * nvn, 1e-7f), 1.f - 1e-5f);
  float Bf = tv * tanhf(tv * atanhf(svv)) / (sc * nvn);
  float x2s = Af * Af * U2, y2s = Bf * Bf * U2, xys = Af * Bf * U2;
  float numc = (1.f + 2.f * c * xys + c * y2s) * Af + (1.f - c * x2s) * Bf;
  float den = fmaxf(1.f + 2.f * c * xys + c * c * x2s * y2s, 1e-7f);
  return numc / den;
}

// ---------------- fused GEMM23 with LN fold: LN(comp) @ [Sg | W2g], 1024 blocks ----------------
__global__ __launch_bounds__(256) void k_gemm23(const unsigned short* __restrict__ comp,
                                                const unsigned short* __restrict__ Sg,
                                                const unsigned short* __restrict__ W2g,
                                                const float* __restrict__ rowsum,
                                                const float* __restrict__ rowsum2,
                                                const float* __restrict__ Gs,
                                                const float* __restrict__ Bs2,
                                                const float* __restrict__ Gw,
                                                const float* __restrict__ Bw,
                                                unsigned short* __restrict__ raw,
                                                float* __restrict__ u2) {
  __shared__ __align__(16) unsigned short As[128 * 64];
  __shared__ __align__(16) unsigned short Bs[128 * 64];
  __shared__ float muS[128], invS[128], GcS[128], BcS[128];
  const int tid = threadIdx.x;
  const int lane = tid & 63;
  const int wave = tid >> 6;
  const int xcd = blockIdx.x & 7;
  const int j = blockIdx.x >> 3;
  const int ntile = j & 15;
  const int bmIdx = xcd + 8 * (j >> 4);
  const int bm = bmIdx * 128;
  const bool isU2 = (ntile < 8);
  const int bn = (ntile & 7) * 128;
  const unsigned short* B = isU2 ? Sg : W2g;

  if (tid < 128) {
    float mu = rowsum[bm + tid] * (1.f / 1024.f);
    float ex2 = rowsum2[bm + tid] * (1.f / 1024.f);
    muS[tid] = mu;
    invS[tid] = rsqrtf(ex2 - mu * mu + 1e-5f);
  } else {
    int c = tid - 128;
    GcS[c] = isU2 ? Gs[bn + c] : Gw[bn + c];
    BcS[c] = isU2 ? Bs2[bn + c] : Bw[bn + c];
  }

  f32x4 acc[4][4] = {};
  gemm_body(comp, B, bm, bn, tid, (char*)As, (char*)Bs, acc);   // has syncthreads

  const int lcol = (wave >> 1) * 64 + (lane & 15);
  const int lrbase = (wave & 1) * 64 + (lane >> 4) * 4;
  #pragma unroll
  for (int mt = 0; mt < 4; ++mt)
    #pragma unroll
    for (int r = 0; r < 4; ++r) {
      const int lrow = lrbase + mt * 16 + r;
      const int row = bm + lrow;
      const float mu = muS[lrow];
      const float inv = invS[lrow];
      if (isU2) {
        float ssq = 0.f;
        #pragma unroll
        for (int nt = 0; nt < 4; ++nt) {
          int c = lcol + nt * 16;
          float v = inv * (acc[mt][nt][r] - mu * GcS[c]) + BcS[c];
          ssq += v * v;
        }
        ssq += __shfl_xor(ssq, 1);
        ssq += __shfl_xor(ssq, 2);
        ssq += __shfl_xor(ssq, 4);
        ssq += __shfl_xor(ssq, 8);
        if ((lane & 15) == 0) atomicAdd(&u2[row], ssq);
      } else {
        #pragma unroll
        for (int nt = 0; nt < 4; ++nt) {
          int c = lcol + nt * 16;
          float v = inv * (acc[mt][nt][r] - mu * GcS[c]) + BcS[c];
          raw[(size_t)row * 1024 + (bn + c)] = f2bf(v);
        }
      }
    }
}

// ---------------- out = gamma(u2[row]) * scale * raw ----------------
__global__ __launch_bounds__(256) void k_out(const unsigned short* __restrict__ raw,
                                             const float* __restrict__ u2,
                                             const float* __restrict__ t_ptr,
                                             const float* __restrict__ scale_ptr,
                                             float* __restrict__ out) {
  __shared__ float gs;
  const int tid = threadIdx.x;
  const int row = blockIdx.x;
  if (tid == 0) gs = gamma_from_u2(u2[row], t_ptr[0]) * scale_ptr[0];
  __syncthreads();
  const float g = gs;
  ushort4 rv = ((const ushort4*)(raw + (size_t)row * 1024))[tid];
  float4 o;
  o.x = bf2f(rv.x) * g;
  o.y = bf2f(rv.y) * g;
  o.z = bf2f(rv.z) * g;
  o.w = bf2f(rv.w) * g;
  ((float4*)(out + (size_t)row * 1024))[tid] = o;
}

// ---------------- extra prep kernel segment: Sc2[k,n] = s[(n-k)] for the W2 GEMM ----------------
__global__ __launch_bounds__(256) void k_sc2(const float* __restrict__ s,
                                             unsigned short* __restrict__ Sc2) {
  int idx = blockIdx.x * 256 + threadIdx.x;   // 262144 ushort4's; k = idx>>8, n0 = (idx&255)*4
  int k = idx >> 8;
  int n0 = (idx & 255) * 4;
  ushort4 o;
  o.x = f2bf(s[(n0 + 0 - k) & 1023]);
  o.y = f2bf(s[(n0 + 1 - k) & 1023]);
  o.z = f2bf(s[(n0 + 2 - k) & 1023]);
  o.w = f2bf(s[(n0 + 3 - k) & 1023]);
  ((ushort4*)Sc2)[idx] = o;
}

extern "C" void kernel_launch(void* const* d_in, const int* in_sizes, int n_in,
                              void* d_out, int out_size, void* d_ws, size_t ws_size,
                              hipStream_t stream) {
  const float* x      = (const float*)d_in[0];
  const float* proj_w = (const float*)d_in[1];
  const float* ln_g   = (const float*)d_in[2];
  const float* ln_b   = (const float*)d_in[3];
  const float* freq_w = (const float*)d_in[4];
  const float* t_p    = (const float*)d_in[5];
  const float* down_w = (const float*)d_in[6];
  const float* scale  = (const float*)d_in[7];

  char* ws = (char*)d_ws;
  unsigned short* xb   = (unsigned short*)ws;                 // 16 MB; reused as raw
  unsigned short* pwb  = (unsigned short*)(ws + (16u << 20)); // 2 MB
  unsigned short* dwb  = (unsigned short*)(ws + (18u << 20)); // 2 MB
  unsigned short* comp = (unsigned short*)(ws + (20u << 20)); // 16 MB
  unsigned short* Sg   = (unsigned short*)(ws + (36u << 20)); // 2 MB  (+2MB Sc2 right after)
  unsigned short* Sc2  = (unsigned short*)(ws + (38u << 20)); // 2 MB  == Sg + 1M elements
  unsigned short* W2g  = (unsigned short*)(ws + (40u << 20)); // 2 MB
  float* s_buf         = (float*)(ws + (42u << 20));          // 4 KB
  float* stats         = (float*)(ws + (42u << 20) + 8192);   // 112 KB zeroed
  float* rowsum  = stats;                 // 8192
  float* rowsum2 = stats + 8192;          // 8192
  float* u2      = stats + 16384;         // 8192
  float* Gw      = stats + 24576;         // 1024
  float* Bw      = stats + 25600;         // 1024
  float* Gs      = stats + 26624;         // 1024
  float* Bs2     = stats + 27648;         // 1024
  unsigned short* raw = xb;               // xb dead after k_gemm1w2

  hipMemsetAsync(stats, 0, 28672 * sizeof(float), stream);
  k_s<<<32, 256, 0, stream>>>(freq_w, s_buf);
  k_prep<<<12288, 256, 0, stream>>>(x, proj_w, down_w, s_buf, ln_g, ln_b,
                                    xb, pwb, dwb, Sg, Gs, Bs2);
  k_sc2<<<1024, 256, 0, stream>>>(s_buf, Sc2);
  k_gemm1w2<<<768, 256, 0, stream>>>(xb, pwb, dwb, Sg, ln_g, ln_b,
                                     comp, W2g, rowsum, rowsum2, Gw, Bw);
  k_gemm23<<<1024, 256, 0, stream>>>(comp, Sg, W2g, rowsum, rowsum2,
                                     Gs, Bs2, Gw, Bw, raw, u2);
  k_out<<<8192, 256, 0, stream>>>(raw, u2, t_p, scale, (float*)d_out);
}

// Round 11
// 200.646 us; speedup vs baseline: 1.0240x; 1.0240x over previous
//
#include <hip/hip_runtime.h>
#include <math.h>

typedef float f32x4 __attribute__((ext_vector_type(4)));
typedef __bf16 bf16x8 __attribute__((ext_vector_type(8)));

__device__ __forceinline__ unsigned short f2bf(float f) {
  unsigned u = __float_as_uint(f);
  unsigned r = (u + 0x7fffu + ((u >> 16) & 1u)) >> 16;
  return (unsigned short)r;
}
__device__ __forceinline__ float bf2f(unsigned short h) {
  return __uint_as_float(((unsigned)h) << 16);
}

// ---------------- block reduction helper ----------------
__device__ __forceinline__ float blk_sum(float v, float* red, int tid) {
  #pragma unroll
  for (int o = 32; o; o >>= 1) v += __shfl_down(v, o);
  __syncthreads();
  if ((tid & 63) == 0) red[tid >> 6] = v;
  __syncthreads();
  return red[0] + red[1] + red[2] + red[3];
}

// ---------------- softmax(freq_w) + s = irfft(softmax), fused ----------------
__global__ __launch_bounds__(256) void k_s(const float* __restrict__ fw,
                                           float* __restrict__ s) {
  __shared__ float wsh[513];
  __shared__ float red[4];
  int tid = threadIdx.x;
  float m = -1e30f;
  for (int i = tid; i < 513; i += 256) m = fmaxf(m, fw[i]);
  #pragma unroll
  for (int o = 32; o; o >>= 1) m = fmaxf(m, __shfl_down(m, o));
  if ((tid & 63) == 0) red[tid >> 6] = m;
  __syncthreads();
  m = fmaxf(fmaxf(red[0], red[1]), fmaxf(red[2], red[3]));
  float sum = 0.f;
  for (int i = tid; i < 513; i += 256) {
    float e = expf(fw[i] - m);
    wsh[i] = e;
    sum += e;
  }
  sum = blk_sum(sum, red, tid);   // syncs inside -> wsh visible after
  float inv = 1.f / sum;

  int gid = blockIdx.x * 256 + tid;   // 8192 threads: d = gid>>3, chunk = gid&7
  int d = gid >> 3;
  int chunk = gid & 7;
  float acc = 0.f;
  for (int f = 1 + chunk; f < 512; f += 8) {
    int p = (f * d) & 1023;
    acc += wsh[f] * __cosf(6.283185307179586f * (float)p * (1.f / 1024.f));
  }
  acc += __shfl_xor(acc, 1);
  acc += __shfl_xor(acc, 2);
  acc += __shfl_xor(acc, 4);
  if (chunk == 0) {
    float tot = wsh[0] + ((d & 1) ? -wsh[512] : wsh[512]) + 2.f * acc;
    s[d] = tot * inv * (1.f / 1024.f);
  }
}

// ---------------- prep: cvt x, cvt proj_w, cvt down_w, fill circulant Sb ----------------
// grid 11264: [0,8192) cvt x; [8192,9216) pw; [9216,10240) dw; [10240,11264) Sb
__global__ __launch_bounds__(256) void k_prep(const float* __restrict__ x,
                                              const float* __restrict__ pw,
                                              const float* __restrict__ dw,
                                              const float* __restrict__ s,
                                              unsigned short* __restrict__ xb,
                                              unsigned short* __restrict__ pwb,
                                              unsigned short* __restrict__ dwb,
                                              unsigned short* __restrict__ Sb) {
  int b = blockIdx.x;
  int tid = threadIdx.x;
  if (b < 8192) {
    int i = b * 256 + tid;
    float4 v = ((const float4*)x)[i];
    ushort4 o;
    o.x = f2bf(v.x); o.y = f2bf(v.y); o.z = f2bf(v.z); o.w = f2bf(v.w);
    ((ushort4*)xb)[i] = o;
  } else if (b < 9216) {
    int i = (b - 8192) * 256 + tid;
    float4 v = ((const float4*)pw)[i];
    ushort4 o;
    o.x = f2bf(v.x); o.y = f2bf(v.y); o.z = f2bf(v.z); o.w = f2bf(v.w);
    ((ushort4*)pwb)[i] = o;
  } else if (b < 10240) {
    int i = (b - 9216) * 256 + tid;
    float4 v = ((const float4*)dw)[i];
    ushort4 o;
    o.x = f2bf(v.x); o.y = f2bf(v.y); o.z = f2bf(v.z); o.w = f2bf(v.w);
    ((ushort4*)dwb)[i] = o;
  } else {
    int idx = (b - 10240) * 256 + tid;    // 262144 ushort4's
    int n = idx >> 8;
    int k0 = (idx & 255) * 4;
    ushort4 o;
    o.x = f2bf(s[(k0 + 0 - n) & 1023]);
    o.y = f2bf(s[(k0 + 1 - n) & 1023]);
    o.z = f2bf(s[(k0 + 2 - n) & 1023]);
    o.w = f2bf(s[(k0 + 3 - n) & 1023]);
    ((ushort4*)Sb)[idx] = o;
  }
}

// ---------------- shared MFMA GEMM body (128x128 tile, K=1024, xor-swizzled LDS) ----------------
__device__ __forceinline__ void gemm_body(const unsigned short* __restrict__ A,
                                          const unsigned short* __restrict__ B,
                                          int bm, int bn, int tid,
                                          char* AsB, char* BsB,
                                          f32x4 acc[4][4]) {
  const int lane = tid & 63;
  const int wave = tid >> 6;
  const int mhalf = (wave & 1) * 64;
  const int nhalf = (wave >> 1) * 64;
  const int ar = tid >> 3;
  const int ac = (((tid & 7) ^ (ar & 7))) * 8;   // xor-swizzled source chunk
  const unsigned short* Abase = A + (size_t)(bm + ar) * 1024 + ac;
  const unsigned short* Bbase = B + (size_t)(bn + ar) * 1024 + ac;
  const int mrow = lane & 15;
  const int kq = lane >> 4;
  const int sw = mrow & 7;

  for (int kt = 0; kt < 16; ++kt) {
    const int k0 = kt * 64;
    #pragma unroll
    for (int r = 0; r < 4; ++r) {
      __builtin_amdgcn_global_load_lds(
          (const __attribute__((address_space(1))) void*)(Abase + (size_t)(r * 32) * 1024 + k0),
          (__attribute__((address_space(3))) void*)(AsB + r * 4096 + wave * 1024), 16, 0, 0);
      __builtin_amdgcn_global_load_lds(
          (const __attribute__((address_space(1))) void*)(Bbase + (size_t)(r * 32) * 1024 + k0),
          (__attribute__((address_space(3))) void*)(BsB + r * 4096 + wave * 1024), 16, 0, 0);
    }
    __syncthreads();
    #pragma unroll
    for (int kc = 0; kc < 2; ++kc) {
      const int chunk = (kc << 2) | kq;
      bf16x8 af[4], bfr[4];
      #pragma unroll
      for (int mt = 0; mt < 4; ++mt)
        af[mt] = *(const bf16x8*)(AsB + (mhalf + mt * 16 + mrow) * 128 + ((chunk ^ sw) << 4));
      #pragma unroll
      for (int nt = 0; nt < 4; ++nt)
        bfr[nt] = *(const bf16x8*)(BsB + (nhalf + nt * 16 + mrow) * 128 + ((chunk ^ sw) << 4));
      #pragma unroll
      for (int mt = 0; mt < 4; ++mt)
        #pragma unroll
        for (int nt = 0; nt < 4; ++nt)
          acc[mt][nt] = __builtin_amdgcn_mfma_f32_16x16x32_bf16(af[mt], bfr[nt], acc[mt][nt], 0, 0, 0);
    }
    __syncthreads();
  }
}

// ---------------- GEMM1 in 128x64 tiles (1024, XCD-swizzled) + W2 64x64 tiles (256, tail) ----------
// grid 1280 = 5 blocks/CU. bid<1024: gemm1 tile (A 128 rows x B 64 rows).
// bid>=1024: W2 = dwb @ Sb^T 64x64 tile (short blocks pack the tail).
__global__ __launch_bounds__(256, 5) void k_gemm1w2(const unsigned short* __restrict__ xb,
                                                    const unsigned short* __restrict__ pwb,
                                                    const unsigned short* __restrict__ dwb,
                                                    const unsigned short* __restrict__ Sb,
                                                    unsigned short* __restrict__ comp,
                                                    unsigned short* __restrict__ W2) {
  __shared__ __align__(16) unsigned short As[128 * 64];   // 16 KB
  __shared__ __align__(16) unsigned short Bs[64 * 64];    // 8 KB
  const int tid = threadIdx.x;
  const int lane = tid & 63;
  const int wave = tid >> 6;
  const int mrow = lane & 15;
  const int kq = lane >> 4;
  const int sw = mrow & 7;
  char* AsB = (char*)As;
  char* BsB = (char*)Bs;

  if (blockIdx.x < 1024) {
    // ---- GEMM1: comp = silu(xb @ pwb^T), 128x64 tile ----
    const int gid = blockIdx.x;
    const int xcd = gid & 7;
    const int j = gid >> 3;                 // 0..127
    const int ntile = j & 15;               // innermost: 16 n-tiles share one A-tile per xcd
    const int bmIdx = xcd + 8 * (j >> 4);   // 0..63
    const int bm = bmIdx * 128;
    const int bn = ntile * 64;
    const int mhalf = (wave & 1) * 64;
    const int nhalf = (wave >> 1) * 32;
    f32x4 acc[4][2] = {};
    const int ar = tid >> 3;
    const int ac = (((tid & 7) ^ (ar & 7))) * 8;
    const unsigned short* Abase = xb + (size_t)(bm + ar) * 1024 + ac;
    const unsigned short* Bbase = pwb + (size_t)(bn + ar) * 1024 + ac;

    for (int kt = 0; kt < 16; ++kt) {
      const int k0 = kt * 64;
      #pragma unroll
      for (int r = 0; r < 4; ++r)
        __builtin_amdgcn_global_load_lds(
            (const __attribute__((address_space(1))) void*)(Abase + (size_t)(r * 32) * 1024 + k0),
            (__attribute__((address_space(3))) void*)(AsB + r * 4096 + wave * 1024), 16, 0, 0);
      #pragma unroll
      for (int r = 0; r < 2; ++r)
        __builtin_amdgcn_global_load_lds(
            (const __attribute__((address_space(1))) void*)(Bbase + (size_t)(r * 32) * 1024 + k0),
            (__attribute__((address_space(3))) void*)(BsB + r * 4096 + wave * 1024), 16, 0, 0);
      __syncthreads();
      #pragma unroll
      for (int kc = 0; kc < 2; ++kc) {
        const int chunk = (kc << 2) | kq;
        bf16x8 af[4], bfr[2];
        #pragma unroll
        for (int mt = 0; mt < 4; ++mt)
          af[mt] = *(const bf16x8*)(AsB + (mhalf + mt * 16 + mrow) * 128 + ((chunk ^ sw) << 4));
        #pragma unroll
        for (int nt = 0; nt < 2; ++nt)
          bfr[nt] = *(const bf16x8*)(BsB + (nhalf + nt * 16 + mrow) * 128 + ((chunk ^ sw) << 4));
        #pragma unroll
        for (int mt = 0; mt < 4; ++mt)
          #pragma unroll
          for (int nt = 0; nt < 2; ++nt)
            acc[mt][nt] = __builtin_amdgcn_mfma_f32_16x16x32_bf16(af[mt], bfr[nt], acc[mt][nt], 0, 0, 0);
      }
      __syncthreads();
    }

    const int col = bn + nhalf + (lane & 15);
    const int rbase = bm + mhalf + (lane >> 4) * 4;
    #pragma unroll
    for (int mt = 0; mt < 4; ++mt)
      #pragma unroll
      for (int r = 0; r < 4; ++r) {
        const int row = rbase + mt * 16 + r;
        #pragma unroll
        for (int nt = 0; nt < 2; ++nt) {
          float v = acc[mt][nt][r];
          comp[(size_t)row * 1024 + (col + nt * 16)] = f2bf(v / (1.f + expf(-v)));
        }
      }
    return;
  }

  // ---- W2 = dwb @ Sb^T, 64x64 tile ----
  const int wbid = blockIdx.x - 1024;     // 0..255
  const int bm = (wbid >> 4) * 64;
  const int bn = (wbid & 15) * 64;
  const int wm = wave & 1;
  const int wn = wave >> 1;
  f32x4 acc[2][2] = {};
  const int ar = tid >> 3;
  const int ac = (((tid & 7) ^ (ar & 7))) * 8;
  const unsigned short* Abase = dwb + (size_t)(bm + ar) * 1024 + ac;
  const unsigned short* Bbase = Sb + (size_t)(bn + ar) * 1024 + ac;
  for (int kt = 0; kt < 16; ++kt) {
    const int k0 = kt * 64;
    #pragma unroll
    for (int r = 0; r < 2; ++r) {
      __builtin_amdgcn_global_load_lds(
          (const __attribute__((address_space(1))) void*)(Abase + (size_t)(r * 32) * 1024 + k0),
          (__attribute__((address_space(3))) void*)(AsB + r * 4096 + wave * 1024), 16, 0, 0);
      __builtin_amdgcn_global_load_lds(
          (const __attribute__((address_space(1))) void*)(Bbase + (size_t)(r * 32) * 1024 + k0),
          (__attribute__((address_space(3))) void*)(BsB + r * 4096 + wave * 1024), 16, 0, 0);
    }
    __syncthreads();
    #pragma unroll
    for (int kc = 0; kc < 2; ++kc) {
      const int chunk = (kc << 2) | kq;
      bf16x8 af[2], bfr[2];
      #pragma unroll
      for (int mt = 0; mt < 2; ++mt)
        af[mt] = *(const bf16x8*)(AsB + (wm * 32 + mt * 16 + mrow) * 128 + ((chunk ^ sw) << 4));
      #pragma unroll
      for (int nt = 0; nt < 2; ++nt)
        bfr[nt] = *(const bf16x8*)(BsB + (wn * 32 + nt * 16 + mrow) * 128 + ((chunk ^ sw) << 4));
      #pragma unroll
      for (int mt = 0; mt < 2; ++mt)
        #pragma unroll
        for (int nt = 0; nt < 2; ++nt)
          acc[mt][nt] = __builtin_amdgcn_mfma_f32_16x16x32_bf16(af[mt], bfr[nt], acc[mt][nt], 0, 0, 0);
    }
    __syncthreads();
  }
  const int col = bn + wn * 32 + (lane & 15);
  const int rbase = bm + wm * 32 + (lane >> 4) * 4;
  #pragma unroll
  for (int mt = 0; mt < 2; ++mt)
    #pragma unroll
    for (int nt = 0; nt < 2; ++nt)
      #pragma unroll
      for (int r = 0; r < 4; ++r) {
        int row = rbase + mt * 16 + r;
        W2[(size_t)row * 1024 + (col + nt * 16)] = f2bf(acc[mt][nt][r]);
      }
}

// ---------------- per-row LayerNorm in place (bf16 -> bf16) + zero U2 ----------------
__global__ __launch_bounds__(256) void k_ln(unsigned short* __restrict__ comp,
                                            const float* __restrict__ ln_g,
                                            const float* __restrict__ ln_b,
                                            float* __restrict__ u2) {
  __shared__ float red[4];
  const int tid = threadIdx.x;
  const size_t rowoff = (size_t)blockIdx.x * 1024;
  if (tid == 0) u2[blockIdx.x] = 0.f;
  ushort4 cv = ((const ushort4*)(comp + rowoff))[tid];
  float x0 = bf2f(cv.x), x1 = bf2f(cv.y), x2 = bf2f(cv.z), x3 = bf2f(cv.w);
  float mu = blk_sum(x0 + x1 + x2 + x3, red, tid) * (1.f / 1024.f);
  float d0 = x0 - mu, d1 = x1 - mu, d2 = x2 - mu, d3 = x3 - mu;
  float var = blk_sum(d0 * d0 + d1 * d1 + d2 * d2 + d3 * d3, red, tid) * (1.f / 1024.f);
  float inv = rsqrtf(var + 1e-5f);
  float4 g = ((const float4*)ln_g)[tid];
  float4 b = ((const float4*)ln_b)[tid];
  ushort4 o;
  o.x = f2bf(d0 * inv * g.x + b.x);
  o.y = f2bf(d1 * inv * g.y + b.y);
  o.z = f2bf(d2 * inv * g.z + b.z);
  o.w = f2bf(d3 * inv * g.w + b.w);
  ((ushort4*)(comp + rowoff))[tid] = o;
}

__device__ __forceinline__ float gamma_from_u2(float U2, float tv) {
  const float sc = 0.01f;      // sqrt(1e-4)
  const float c = 1e-4f;
  float nrm = sqrtf(U2);
  float nu = fmaxf(nrm, 1e-7f);
  float su = fminf(fmaxf(sc * nu, 1e-7f), 1.f - 1e-5f);
  float Af = tanhf((1.f - tv) * atanhf(su)) / (sc * nu);
  float nvn = fmaxf(fabsf(tv) * nrm, 1e-7f);
  float svv = fminf(fmaxf(sc * nvn, 1e-7f), 1.f - 1e-5f);
  float Bf = tv * tanhf(tv * atanhf(svv)) / (sc * nvn);
  float x2s = Af * Af * U2, y2s = Bf * Bf * U2, xys = Af * Bf * U2;
  float numc = (1.f + 2.f * c * xys + c * y2s) * Af + (1.f - c * x2s) * Bf;
  float den = fmaxf(1.f + 2.f * c * xys + c * c * x2s * y2s, 1e-7f);
  return numc / den;
}

// ---------------- fused GEMM23: comp @ [Sc | W2], 1024 blocks, XCD-swizzled ----------------
__global__ __launch_bounds__(256) void k_gemm23(const unsigned short* __restrict__ comp,
                                                const unsigned short* __restrict__ Sb,
                                                const unsigned short* __restrict__ W2,
                                                unsigned short* __restrict__ raw,
                                                float* __restrict__ u2) {
  __shared__ __align__(16) unsigned short As[128 * 64];
  __shared__ __align__(16) unsigned short Bs[128 * 64];
  const int tid = threadIdx.x;
  const int lane = tid & 63;
  const int wave = tid >> 6;
  const int xcd = blockIdx.x & 7;
  const int j = blockIdx.x >> 3;          // 0..127
  const int ntile = j & 15;               // innermost: 16 n-tiles share one A-tile per xcd
  const int bmIdx = xcd + 8 * (j >> 4);   // 0..63
  const int bm = bmIdx * 128;
  const bool isU2 = (ntile < 8);
  const int bn = (ntile & 7) * 128;
  const unsigned short* B = isU2 ? Sb : W2;
  f32x4 acc[4][4] = {};
  gemm_body(comp, B, bm, bn, tid, (char*)As, (char*)Bs, acc);

  const int col = bn + (wave >> 1) * 64 + (lane & 15);
  const int rbase = bm + (wave & 1) * 64 + (lane >> 4) * 4;
  #pragma unroll
  for (int mt = 0; mt < 4; ++mt)
    #pragma unroll
    for (int r = 0; r < 4; ++r) {
      const int row = rbase + mt * 16 + r;
      if (isU2) {
        float v0 = acc[mt][0][r], v1 = acc[mt][1][r], v2 = acc[mt][2][r], v3 = acc[mt][3][r];
        float ssq = v0 * v0 + v1 * v1 + v2 * v2 + v3 * v3;
        ssq += __shfl_xor(ssq, 1);
        ssq += __shfl_xor(ssq, 2);
        ssq += __shfl_xor(ssq, 4);
        ssq += __shfl_xor(ssq, 8);
        if ((lane & 15) == 0) atomicAdd(&u2[row], ssq);
      } else {
        #pragma unroll
        for (int nt = 0; nt < 4; ++nt)
          raw[(size_t)row * 1024 + (col + nt * 16)] = f2bf(acc[mt][nt][r]);
      }
    }
}

// ---------------- out = gamma(u2[row]) * scale * raw ----------------
__global__ __launch_bounds__(256) void k_out(const unsigned short* __restrict__ raw,
                                             const float* __restrict__ u2,
                                             const float* __restrict__ t_ptr,
                                             const float* __restrict__ scale_ptr,
                                             float* __restrict__ out) {
  __shared__ float gs;
  const int tid = threadIdx.x;
  const int row = blockIdx.x;
  if (tid == 0) gs = gamma_from_u2(u2[row], t_ptr[0]) * scale_ptr[0];
  __syncthreads();
  const float g = gs;
  ushort4 rv = ((const ushort4*)(raw + (size_t)row * 1024))[tid];
  float4 o;
  o.x = bf2f(rv.x) * g;
  o.y = bf2f(rv.y) * g;
  o.z = bf2f(rv.z) * g;
  o.w = bf2f(rv.w) * g;
  ((float4*)(out + (size_t)row * 1024))[tid] = o;
}

extern "C" void kernel_launch(void* const* d_in, const int* in_sizes, int n_in,
                              void* d_out, int out_size, void* d_ws, size_t ws_size,
                              hipStream_t stream) {
  const float* x      = (const float*)d_in[0];
  const float* proj_w = (const float*)d_in[1];
  const float* ln_g   = (const float*)d_in[2];
  const float* ln_b   = (const float*)d_in[3];
  const float* freq_w = (const float*)d_in[4];
  const float* t_p    = (const float*)d_in[5];
  const float* down_w = (const float*)d_in[6];
  const float* scale  = (const float*)d_in[7];

  char* ws = (char*)d_ws;
  unsigned short* xb   = (unsigned short*)ws;                 // 16 MB; reused as raw
  unsigned short* pwb  = (unsigned short*)(ws + (16u << 20)); // 2 MB
  unsigned short* dwb  = (unsigned short*)(ws + (18u << 20)); // 2 MB
  unsigned short* comp = (unsigned short*)(ws + (20u << 20)); // 16 MB
  unsigned short* Sb   = (unsigned short*)(ws + (36u << 20)); // 2 MB
  unsigned short* W2   = (unsigned short*)(ws + (38u << 20)); // 2 MB
  float* s_buf         = (float*)(ws + (40u << 20));          // 4 KB
  float* u2            = (float*)(ws + (40u << 20) + 8192);   // 32 KB
  unsigned short* raw  = xb;   // xb dead after k_gemm1w2

  k_s<<<32, 256, 0, stream>>>(freq_w, s_buf);
  k_prep<<<11264, 256, 0, stream>>>(x, proj_w, down_w, s_buf, xb, pwb, dwb, Sb);
  k_gemm1w2<<<1280, 256, 0, stream>>>(xb, pwb, dwb, Sb, comp, W2);
  k_ln<<<8192, 256, 0, stream>>>(comp, ln_g, ln_b, u2);
  k_gemm23<<<1024, 256, 0, stream>>>(comp, Sb, W2, raw, u2);
  k_out<<<8192, 256, 0, stream>>>(raw, u2, t_p, scale, (float*)d_out);
}

// Round 12
// 194.544 us; speedup vs baseline: 1.0561x; 1.0314x over previous
//
#include <hip/hip_runtime.h>
#include <math.h>

typedef float f32x4 __attribute__((ext_vector_type(4)));
typedef __bf16 bf16x8 __attribute__((ext_vector_type(8)));

__device__ __forceinline__ unsigned short f2bf(float f) {
  unsigned u = __float_as_uint(f);
  unsigned r = (u + 0x7fffu + ((u >> 16) & 1u)) >> 16;
  return (unsigned short)r;
}
__device__ __forceinline__ float bf2f(unsigned short h) {
  return __uint_as_float(((unsigned)h) << 16);
}

// ---------------- block reduction helper ----------------
__device__ __forceinline__ float blk_sum(float v, float* red, int tid) {
  #pragma unroll
  for (int o = 32; o; o >>= 1) v += __shfl_down(v, o);
  __syncthreads();
  if ((tid & 63) == 0) red[tid >> 6] = v;
  __syncthreads();
  return red[0] + red[1] + red[2] + red[3];
}

// ---------------- softmax(freq_w) + s = irfft(softmax), fused ----------------
__global__ __launch_bounds__(256) void k_s(const float* __restrict__ fw,
                                           float* __restrict__ s) {
  __shared__ float wsh[513];
  __shared__ float red[4];
  int tid = threadIdx.x;
  float m = -1e30f;
  for (int i = tid; i < 513; i += 256) m = fmaxf(m, fw[i]);
  #pragma unroll
  for (int o = 32; o; o >>= 1) m = fmaxf(m, __shfl_down(m, o));
  if ((tid & 63) == 0) red[tid >> 6] = m;
  __syncthreads();
  m = fmaxf(fmaxf(red[0], red[1]), fmaxf(red[2], red[3]));
  float sum = 0.f;
  for (int i = tid; i < 513; i += 256) {
    float e = expf(fw[i] - m);
    wsh[i] = e;
    sum += e;
  }
  sum = blk_sum(sum, red, tid);   // syncs inside -> wsh visible after
  float inv = 1.f / sum;

  int gid = blockIdx.x * 256 + tid;   // 8192 threads: d = gid>>3, chunk = gid&7
  int d = gid >> 3;
  int chunk = gid & 7;
  float acc = 0.f;
  for (int f = 1 + chunk; f < 512; f += 8) {
    int p = (f * d) & 1023;
    acc += wsh[f] * __cosf(6.283185307179586f * (float)p * (1.f / 1024.f));
  }
  acc += __shfl_xor(acc, 1);
  acc += __shfl_xor(acc, 2);
  acc += __shfl_xor(acc, 4);
  if (chunk == 0) {
    float tot = wsh[0] + ((d & 1) ? -wsh[512] : wsh[512]) + 2.f * acc;
    s[d] = tot * inv * (1.f / 1024.f);
  }
}

// ---------------- prep: cvt x, cvt proj_w, cvt down_w, fill circulant Sb ----------------
// grid 11264: [0,8192) cvt x; [8192,9216) pw; [9216,10240) dw; [10240,11264) Sb
__global__ __launch_bounds__(256) void k_prep(const float* __restrict__ x,
                                              const float* __restrict__ pw,
                                              const float* __restrict__ dw,
                                              const float* __restrict__ s,
                                              unsigned short* __restrict__ xb,
                                              unsigned short* __restrict__ pwb,
                                              unsigned short* __restrict__ dwb,
                                              unsigned short* __restrict__ Sb) {
  int b = blockIdx.x;
  int tid = threadIdx.x;
  if (b < 8192) {
    int i = b * 256 + tid;
    float4 v = ((const float4*)x)[i];
    ushort4 o;
    o.x = f2bf(v.x); o.y = f2bf(v.y); o.z = f2bf(v.z); o.w = f2bf(v.w);
    ((ushort4*)xb)[i] = o;
  } else if (b < 9216) {
    int i = (b - 8192) * 256 + tid;
    float4 v = ((const float4*)pw)[i];
    ushort4 o;
    o.x = f2bf(v.x); o.y = f2bf(v.y); o.z = f2bf(v.z); o.w = f2bf(v.w);
    ((ushort4*)pwb)[i] = o;
  } else if (b < 10240) {
    int i = (b - 9216) * 256 + tid;
    float4 v = ((const float4*)dw)[i];
    ushort4 o;
    o.x = f2bf(v.x); o.y = f2bf(v.y); o.z = f2bf(v.z); o.w = f2bf(v.w);
    ((ushort4*)dwb)[i] = o;
  } else {
    int idx = (b - 10240) * 256 + tid;    // 262144 ushort4's
    int n = idx >> 8;
    int k0 = (idx & 255) * 4;
    ushort4 o;
    o.x = f2bf(s[(k0 + 0 - n) & 1023]);
    o.y = f2bf(s[(k0 + 1 - n) & 1023]);
    o.z = f2bf(s[(k0 + 2 - n) & 1023]);
    o.w = f2bf(s[(k0 + 3 - n) & 1023]);
    ((ushort4*)Sb)[idx] = o;
  }
}

// ---------------- shared MFMA GEMM body (128x128 tile, K=1024, xor-swizzled LDS) ----------------
__device__ __forceinline__ void gemm_body(const unsigned short* __restrict__ A,
                                          const unsigned short* __restrict__ B,
                                          int bm, int bn, int tid,
                                          char* AsB, char* BsB,
                                          f32x4 acc[4][4]) {
  const int lane = tid & 63;
  const int wave = tid >> 6;
  const int mhalf = (wave & 1) * 64;
  const int nhalf = (wave >> 1) * 64;
  const int ar = tid >> 3;
  const int ac = (((tid & 7) ^ (ar & 7))) * 8;   // xor-swizzled source chunk
  const unsigned short* Abase = A + (size_t)(bm + ar) * 1024 + ac;
  const unsigned short* Bbase = B + (size_t)(bn + ar) * 1024 + ac;
  const int mrow = lane & 15;
  const int kq = lane >> 4;
  const int sw = mrow & 7;

  for (int kt = 0; kt < 16; ++kt) {
    const int k0 = kt * 64;
    #pragma unroll
    for (int r = 0; r < 4; ++r) {
      __builtin_amdgcn_global_load_lds(
          (const __attribute__((address_space(1))) void*)(Abase + (size_t)(r * 32) * 1024 + k0),
          (__attribute__((address_space(3))) void*)(AsB + r * 4096 + wave * 1024), 16, 0, 0);
      __builtin_amdgcn_global_load_lds(
          (const __attribute__((address_space(1))) void*)(Bbase + (size_t)(r * 32) * 1024 + k0),
          (__attribute__((address_space(3))) void*)(BsB + r * 4096 + wave * 1024), 16, 0, 0);
    }
    __syncthreads();
    #pragma unroll
    for (int kc = 0; kc < 2; ++kc) {
      const int chunk = (kc << 2) | kq;
      bf16x8 af[4], bfr[4];
      #pragma unroll
      for (int mt = 0; mt < 4; ++mt)
        af[mt] = *(const bf16x8*)(AsB + (mhalf + mt * 16 + mrow) * 128 + ((chunk ^ sw) << 4));
      #pragma unroll
      for (int nt = 0; nt < 4; ++nt)
        bfr[nt] = *(const bf16x8*)(BsB + (nhalf + nt * 16 + mrow) * 128 + ((chunk ^ sw) << 4));
      #pragma unroll
      for (int mt = 0; mt < 4; ++mt)
        #pragma unroll
        for (int nt = 0; nt < 4; ++nt)
          acc[mt][nt] = __builtin_amdgcn_mfma_f32_16x16x32_bf16(af[mt], bfr[nt], acc[mt][nt], 0, 0, 0);
    }
    __syncthreads();
  }
}

// ---------------- GEMM1 in 128x64 tiles (1024, XCD-swizzled) + W2 64x64 tiles (256, tail) ----------
// grid 1280 = 5 blocks/CU. bid<1024: gemm1 tile (A 128 rows x B 64 rows).
// bid>=1024: W2 = dwb @ Sb^T 64x64 tile (short blocks pack the tail).
__global__ __launch_bounds__(256, 5) void k_gemm1w2(const unsigned short* __restrict__ xb,
                                                    const unsigned short* __restrict__ pwb,
                                                    const unsigned short* __restrict__ dwb,
                                                    const unsigned short* __restrict__ Sb,
                                                    unsigned short* __restrict__ comp,
                                                    unsigned short* __restrict__ W2) {
  __shared__ __align__(16) unsigned short As[128 * 64];   // 16 KB
  __shared__ __align__(16) unsigned short Bs[64 * 64];    // 8 KB
  const int tid = threadIdx.x;
  const int lane = tid & 63;
  const int wave = tid >> 6;
  const int mrow = lane & 15;
  const int kq = lane >> 4;
  const int sw = mrow & 7;
  char* AsB = (char*)As;
  char* BsB = (char*)Bs;

  if (blockIdx.x < 1024) {
    // ---- GEMM1: comp = silu(xb @ pwb^T), 128x64 tile ----
    const int gid = blockIdx.x;
    const int xcd = gid & 7;
    const int j = gid >> 3;                 // 0..127
    const int ntile = j & 15;               // innermost: 16 n-tiles share one A-tile per xcd
    const int bmIdx = xcd + 8 * (j >> 4);   // 0..63
    const int bm = bmIdx * 128;
    const int bn = ntile * 64;
    const int mhalf = (wave & 1) * 64;
    const int nhalf = (wave >> 1) * 32;
    f32x4 acc[4][2] = {};
    const int ar = tid >> 3;
    const int ac = (((tid & 7) ^ (ar & 7))) * 8;
    const unsigned short* Abase = xb + (size_t)(bm + ar) * 1024 + ac;
    const unsigned short* Bbase = pwb + (size_t)(bn + ar) * 1024 + ac;

    for (int kt = 0; kt < 16; ++kt) {
      const int k0 = kt * 64;
      #pragma unroll
      for (int r = 0; r < 4; ++r)
        __builtin_amdgcn_global_load_lds(
            (const __attribute__((address_space(1))) void*)(Abase + (size_t)(r * 32) * 1024 + k0),
            (__attribute__((address_space(3))) void*)(AsB + r * 4096 + wave * 1024), 16, 0, 0);
      #pragma unroll
      for (int r = 0; r < 2; ++r)
        __builtin_amdgcn_global_load_lds(
            (const __attribute__((address_space(1))) void*)(Bbase + (size_t)(r * 32) * 1024 + k0),
            (__attribute__((address_space(3))) void*)(BsB + r * 4096 + wave * 1024), 16, 0, 0);
      __syncthreads();
      #pragma unroll
      for (int kc = 0; kc < 2; ++kc) {
        const int chunk = (kc << 2) | kq;
        bf16x8 af[4], bfr[2];
        #pragma unroll
        for (int mt = 0; mt < 4; ++mt)
          af[mt] = *(const bf16x8*)(AsB + (mhalf + mt * 16 + mrow) * 128 + ((chunk ^ sw) << 4));
        #pragma unroll
        for (int nt = 0; nt < 2; ++nt)
          bfr[nt] = *(const bf16x8*)(BsB + (nhalf + nt * 16 + mrow) * 128 + ((chunk ^ sw) << 4));
        #pragma unroll
        for (int mt = 0; mt < 4; ++mt)
          #pragma unroll
          for (int nt = 0; nt < 2; ++nt)
            acc[mt][nt] = __builtin_amdgcn_mfma_f32_16x16x32_bf16(af[mt], bfr[nt], acc[mt][nt], 0, 0, 0);
      }
      __syncthreads();
    }

    const int col = bn + nhalf + (lane & 15);
    const int rbase = bm + mhalf + (lane >> 4) * 4;
    #pragma unroll
    for (int mt = 0; mt < 4; ++mt)
      #pragma unroll
      for (int r = 0; r < 4; ++r) {
        const int row = rbase + mt * 16 + r;
        #pragma unroll
        for (int nt = 0; nt < 2; ++nt) {
          float v = acc[mt][nt][r];
          comp[(size_t)row * 1024 + (col + nt * 16)] = f2bf(v / (1.f + expf(-v)));
        }
      }
    return;
  }

  // ---- W2 = dwb @ Sb^T, 64x64 tile ----
  const int wbid = blockIdx.x - 1024;     // 0..255
  const int bm = (wbid >> 4) * 64;
  const int bn = (wbid & 15) * 64;
  const int wm = wave & 1;
  const int wn = wave >> 1;
  f32x4 acc[2][2] = {};
  const int ar = tid >> 3;
  const int ac = (((tid & 7) ^ (ar & 7))) * 8;
  const unsigned short* Abase = dwb + (size_t)(bm + ar) * 1024 + ac;
  const unsigned short* Bbase = Sb + (size_t)(bn + ar) * 1024 + ac;
  for (int kt = 0; kt < 16; ++kt) {
    const int k0 = kt * 64;
    #pragma unroll
    for (int r = 0; r < 2; ++r) {
      __builtin_amdgcn_global_load_lds(
          (const __attribute__((address_space(1))) void*)(Abase + (size_t)(r * 32) * 1024 + k0),
          (__attribute__((address_space(3))) void*)(AsB + r * 4096 + wave * 1024), 16, 0, 0);
      __builtin_amdgcn_global_load_lds(
          (const __attribute__((address_space(1))) void*)(Bbase + (size_t)(r * 32) * 1024 + k0),
          (__attribute__((address_space(3))) void*)(BsB + r * 4096 + wave * 1024), 16, 0, 0);
    }
    __syncthreads();
    #pragma unroll
    for (int kc = 0; kc < 2; ++kc) {
      const int chunk = (kc << 2) | kq;
      bf16x8 af[2], bfr[2];
      #pragma unroll
      for (int mt = 0; mt < 2; ++mt)
        af[mt] = *(const bf16x8*)(AsB + (wm * 32 + mt * 16 + mrow) * 128 + ((chunk ^ sw) << 4));
      #pragma unroll
      for (int nt = 0; nt < 2; ++nt)
        bfr[nt] = *(const bf16x8*)(BsB + (wn * 32 + nt * 16 + mrow) * 128 + ((chunk ^ sw) << 4));
      #pragma unroll
      for (int mt = 0; mt < 2; ++mt)
        #pragma unroll
        for (int nt = 0; nt < 2; ++nt)
          acc[mt][nt] = __builtin_amdgcn_mfma_f32_16x16x32_bf16(af[mt], bfr[nt], acc[mt][nt], 0, 0, 0);
    }
    __syncthreads();
  }
  const int col = bn + wn * 32 + (lane & 15);
  const int rbase = bm + wm * 32 + (lane >> 4) * 4;
  #pragma unroll
  for (int mt = 0; mt < 2; ++mt)
    #pragma unroll
    for (int nt = 0; nt < 2; ++nt)
      #pragma unroll
      for (int r = 0; r < 4; ++r) {
        int row = rbase + mt * 16 + r;
        W2[(size_t)row * 1024 + (col + nt * 16)] = f2bf(acc[mt][nt][r]);
      }
}

// ---------------- per-row LayerNorm in place (bf16 -> bf16) + zero U2 ----------------
__global__ __launch_bounds__(256) void k_ln(unsigned short* __restrict__ comp,
                                            const float* __restrict__ ln_g,
                                            const float* __restrict__ ln_b,
                                            float* __restrict__ u2) {
  __shared__ float red[4];
  const int tid = threadIdx.x;
  const size_t rowoff = (size_t)blockIdx.x * 1024;
  if (tid == 0) u2[blockIdx.x] = 0.f;
  ushort4 cv = ((const ushort4*)(comp + rowoff))[tid];
  float x0 = bf2f(cv.x), x1 = bf2f(cv.y), x2 = bf2f(cv.z), x3 = bf2f(cv.w);
  float mu = blk_sum(x0 + x1 + x2 + x3, red, tid) * (1.f / 1024.f);
  float d0 = x0 - mu, d1 = x1 - mu, d2 = x2 - mu, d3 = x3 - mu;
  float var = blk_sum(d0 * d0 + d1 * d1 + d2 * d2 + d3 * d3, red, tid) * (1.f / 1024.f);
  float inv = rsqrtf(var + 1e-5f);
  float4 g = ((const float4*)ln_g)[tid];
  float4 b = ((const float4*)ln_b)[tid];
  ushort4 o;
  o.x = f2bf(d0 * inv * g.x + b.x);
  o.y = f2bf(d1 * inv * g.y + b.y);
  o.z = f2bf(d2 * inv * g.z + b.z);
  o.w = f2bf(d3 * inv * g.w + b.w);
  ((ushort4*)(comp + rowoff))[tid] = o;
}

__device__ __forceinline__ float gamma_from_u2(float U2, float tv) {
  const float sc = 0.01f;      // sqrt(1e-4)
  const float c = 1e-4f;
  float nrm = sqrtf(U2);
  float nu = fmaxf(nrm, 1e-7f);
  float su = fminf(fmaxf(sc * nu, 1e-7f), 1.f - 1e-5f);
  float Af = tanhf((1.f - tv) * atanhf(su)) / (sc * nu);
  float nvn = fmaxf(fabsf(tv) * nrm, 1e-7f);
  float svv = fminf(fmaxf(sc * nvn, 1e-7f), 1.f - 1e-5f);
  float Bf = tv * tanhf(tv * atanhf(svv)) / (sc * nvn);
  float x2s = Af * Af * U2, y2s = Bf * Bf * U2, xys = Af * Bf * U2;
  float numc = (1.f + 2.f * c * xys + c * y2s) * Af + (1.f - c * x2s) * Bf;
  float den = fmaxf(1.f + 2.f * c * xys + c * c * x2s * y2s, 1e-7f);
  return numc / den;
}

// ---------------- fused GEMM23: comp @ [Sc | W2], 1024 blocks, XCD-swizzled ----------------
// launch_bounds(256,5): cap VGPR <=102 so all 1024 blocks are co-resident
// (LDS 32KB allows exactly 5/CU; R11's VGPR=108 capped occupancy at 4/CU).
__global__ __launch_bounds__(256, 5) void k_gemm23(const unsigned short* __restrict__ comp,
                                                   const unsigned short* __restrict__ Sb,
                                                   const unsigned short* __restrict__ W2,
                                                   unsigned short* __restrict__ raw,
                                                   float* __restrict__ u2) {
  __shared__ __align__(16) unsigned short As[128 * 64];
  __shared__ __align__(16) unsigned short Bs[128 * 64];
  const int tid = threadIdx.x;
  const int lane = tid & 63;
  const int wave = tid >> 6;
  const int xcd = blockIdx.x & 7;
  const int j = blockIdx.x >> 3;          // 0..127
  const int ntile = j & 15;               // innermost: 16 n-tiles share one A-tile per xcd
  const int bmIdx = xcd + 8 * (j >> 4);   // 0..63
  const int bm = bmIdx * 128;
  const bool isU2 = (ntile < 8);
  const int bn = (ntile & 7) * 128;
  const unsigned short* B = isU2 ? Sb : W2;
  f32x4 acc[4][4] = {};
  gemm_body(comp, B, bm, bn, tid, (char*)As, (char*)Bs, acc);

  const int col = bn + (wave >> 1) * 64 + (lane & 15);
  const int rbase = bm + (wave & 1) * 64 + (lane >> 4) * 4;
  #pragma unroll
  for (int mt = 0; mt < 4; ++mt)
    #pragma unroll
    for (int r = 0; r < 4; ++r) {
      const int row = rbase + mt * 16 + r;
      if (isU2) {
        float v0 = acc[mt][0][r], v1 = acc[mt][1][r], v2 = acc[mt][2][r], v3 = acc[mt][3][r];
        float ssq = v0 * v0 + v1 * v1 + v2 * v2 + v3 * v3;
        ssq += __shfl_xor(ssq, 1);
        ssq += __shfl_xor(ssq, 2);
        ssq += __shfl_xor(ssq, 4);
        ssq += __shfl_xor(ssq, 8);
        if ((lane & 15) == 0) atomicAdd(&u2[row], ssq);
      } else {
        #pragma unroll
        for (int nt = 0; nt < 4; ++nt)
          raw[(size_t)row * 1024 + (col + nt * 16)] = f2bf(acc[mt][nt][r]);
      }
    }
}

// ---------------- out = gamma(u2[row]) * scale * raw ----------------
__global__ __launch_bounds__(256) void k_out(const unsigned short* __restrict__ raw,
                                             const float* __restrict__ u2,
                                             const float* __restrict__ t_ptr,
                                             const float* __restrict__ scale_ptr,
                                             float* __restrict__ out) {
  __shared__ float gs;
  const int tid = threadIdx.x;
  const int row = blockIdx.x;
  if (tid == 0) gs = gamma_from_u2(u2[row], t_ptr[0]) * scale_ptr[0];
  __syncthreads();
  const float g = gs;
  ushort4 rv = ((const ushort4*)(raw + (size_t)row * 1024))[tid];
  float4 o;
  o.x = bf2f(rv.x) * g;
  o.y = bf2f(rv.y) * g;
  o.z = bf2f(rv.z) * g;
  o.w = bf2f(rv.w) * g;
  ((float4*)(out + (size_t)row * 1024))[tid] = o;
}

extern "C" void kernel_launch(void* const* d_in, const int* in_sizes, int n_in,
                              void* d_out, int out_size, void* d_ws, size_t ws_size,
                              hipStream_t stream) {
  const float* x      = (const float*)d_in[0];
  const float* proj_w = (const float*)d_in[1];
  const float* ln_g   = (const float*)d_in[2];
  const float* ln_b   = (const float*)d_in[3];
  const float* freq_w = (const float*)d_in[4];
  const float* t_p    = (const float*)d_in[5];
  const float* down_w = (const float*)d_in[6];
  const float* scale  = (const float*)d_in[7];

  char* ws = (char*)d_ws;
  unsigned short* xb   = (unsigned short*)ws;                 // 16 MB; reused as raw
  unsigned short* pwb  = (unsigned short*)(ws + (16u << 20)); // 2 MB
  unsigned short* dwb  = (unsigned short*)(ws + (18u << 20)); // 2 MB
  unsigned short* comp = (unsigned short*)(ws + (20u << 20)); // 16 MB
  unsigned short* Sb   = (unsigned short*)(ws + (36u << 20)); // 2 MB
  unsigned short* W2   = (unsigned short*)(ws + (38u << 20)); // 2 MB
  float* s_buf         = (float*)(ws + (40u << 20));          // 4 KB
  float* u2            = (float*)(ws + (40u << 20) + 8192);   // 32 KB
  unsigned short* raw  = xb;   // xb dead after k_gemm1w2

  k_s<<<32, 256, 0, stream>>>(freq_w, s_buf);
  k_prep<<<11264, 256, 0, stream>>>(x, proj_w, down_w, s_buf, xb, pwb, dwb, Sb);
  k_gemm1w2<<<1280, 256, 0, stream>>>(xb, pwb, dwb, Sb, comp, W2);
  k_ln<<<8192, 256, 0, stream>>>(comp, ln_g, ln_b, u2);
  k_gemm23<<<1024, 256, 0, stream>>>(comp, Sb, W2, raw, u2);
  k_out<<<8192, 256, 0, stream>>>(raw, u2, t_p, scale, (float*)d_out);
}